// Round 13
// baseline (207.801 us; speedup 1.0000x reference)
//
#include <hip/hip_runtime.h>

// GCN 2-layer encoder for MI355X (gfx950) — round 13.
// r12 post-mortem: count+gemm1 = 63us, WRITE_SIZE 2.2x payload -> contended
// atomicAdd-return on the 200KB indeg array ping-pongs lines across the 8
// non-coherent XCD L2s (12-way avg contention per node). r13:
//   (a) 8-sharded count: indeg8[c][n], shard c = blockIdx&7 (round-robin
//       block->XCD) -> atomics stay XCD-L2-local. rank = rank within (c,d);
//       fill position = base8[d][c] + rank, base8 built in scan3.
//   (b) gemm1 / count8 / fill all STANDALONE -> direct attribution of the
//       three never-measured costs.
//
// Pipeline (8 dispatches):
//   k_init(zero indeg8 || split W1,W2) -> k_gemm1 -> k_count8 ->
//   k_scan1(prefix+dinv) -> k_scan3(row_ptr offs + base8) -> k_fill ->
//   k_gather_gemm2 -> k_gather64

constexpr int IN_CH  = 128;
constexpr int HID    = 128;
constexpr int OUT_CH = 64;
constexpr int SCAN_CHUNK = 4096;
constexpr int NSH = 8;           // count shards (== XCDs)
constexpr int CTILE = 1024;      // edges per count block (256 thr x 4)

using short8v = __attribute__((ext_vector_type(8))) short;
using f32x4v  = __attribute__((ext_vector_type(4))) float;

__device__ __forceinline__ unsigned short f2bf_rne(float f) {
    unsigned int u = __float_as_uint(f);
    u += 0x7FFFu + ((u >> 16) & 1u);
    return (unsigned short)(u >> 16);
}
__device__ __forceinline__ float bf2f(unsigned short h) {
    return __uint_as_float((unsigned int)h << 16);
}

__device__ __forceinline__ bool probe_is64(const int* __restrict__ ei) {
    const int v = ei[2 * (threadIdx.x & 63) + 1];
    return __ballot(v != 0) == 0ull;
}

__device__ __forceinline__ void load_idx4(const int* __restrict__ ei, bool is64,
                                          long long hb, int e0, int n, int* out) {
    const long long p = hb + e0;
    if (is64) {
        if (n == 4 && ((p & 1) == 0)) {
            const int4 a = *reinterpret_cast<const int4*>(ei + 2 * p);
            const int4 b = *reinterpret_cast<const int4*>(ei + 2 * p + 4);
            out[0] = a.x; out[1] = a.z; out[2] = b.x; out[3] = b.z;
        } else {
            for (int j = 0; j < n; ++j) out[j] = ei[2 * (p + j)];
        }
    } else {
        if (n == 4 && ((p & 3) == 0)) {
            const int4 a = *reinterpret_cast<const int4*>(ei + p);
            out[0] = a.x; out[1] = a.y; out[2] = a.z; out[3] = a.w;
        } else {
            for (int j = 0; j < n; ++j) out[j] = ei[p + j];
        }
    }
}

// 8 bf16 (one uint4) fma into two float4 accumulators.
__device__ __forceinline__ void fma8(float4& a0, float4& a1, uint4 u, float w) {
    a0.x = fmaf(__uint_as_float(u.x << 16), w, a0.x);
    a0.y = fmaf(__uint_as_float(u.x & 0xffff0000u), w, a0.y);
    a0.z = fmaf(__uint_as_float(u.y << 16), w, a0.z);
    a0.w = fmaf(__uint_as_float(u.y & 0xffff0000u), w, a0.w);
    a1.x = fmaf(__uint_as_float(u.z << 16), w, a1.x);
    a1.y = fmaf(__uint_as_float(u.z & 0xffff0000u), w, a1.y);
    a1.z = fmaf(__uint_as_float(u.w << 16), w, a1.z);
    a1.w = fmaf(__uint_as_float(u.w & 0xffff0000u), w, a1.w);
}

// blocks 0..63: zero indeg8 (NSH*N ints). 64..79: split W1. 80..87: split W2.
__global__ __launch_bounds__(256) void k_init(int* __restrict__ indeg8, int M8,
                                              const float* __restrict__ W1,
                                              const float* __restrict__ W2,
                                              unsigned short* __restrict__ w1th,
                                              unsigned short* __restrict__ w1tl,
                                              unsigned short* __restrict__ w2th,
                                              unsigned short* __restrict__ w2tl) {
    const int b = blockIdx.x;
    if (b < 64) {
        const int i = b * 256 + threadIdx.x;
        const int n4 = M8 / 4;
        for (int j = i; j < n4; j += 64 * 256)
            reinterpret_cast<int4*>(indeg8)[j] = make_int4(0, 0, 0, 0);
        const int tail = n4 * 4 + i;
        if (tail < M8) indeg8[tail] = 0;
    } else if (b < 80) {
        const int i = (b - 64) * 1024 + threadIdx.x * 4;
        const int n = i >> 7, k = i & 127;
#pragma unroll
        for (int j = 0; j < 4; ++j) {
            const float f = W1[(size_t)(k + j) * HID + n];
            const unsigned short h = f2bf_rne(f);
            w1th[n * 128 + k + j] = h;
            w1tl[n * 128 + k + j] = f2bf_rne(f - bf2f(h));
        }
    } else {
        const int i = (b - 80) * 1024 + threadIdx.x * 4;
        const int n = i >> 7, k = i & 127;
#pragma unroll
        for (int j = 0; j < 4; ++j) {
            const float f = W2[(size_t)(k + j) * OUT_CH + n];
            const unsigned short h = f2bf_rne(f);
            w2th[n * 128 + k + j] = h;
            w2tl[n * 128 + k + j] = f2bf_rne(f - bf2f(h));
        }
    }
}

// MFMA GEMM1, LDS-free, STANDALONE: h1b = x @ W1 split-precision.
__global__ __launch_bounds__(256) void k_gemm1(const float* __restrict__ X,
                                               const unsigned short* __restrict__ w1th,
                                               const unsigned short* __restrict__ w1tl,
                                               unsigned short* __restrict__ Y, int M) {
    const int tid = threadIdx.x;
    const int wv  = tid >> 6;
    const int ln  = tid & 63;
    const int m16 = ln & 15;
    const int g   = ln >> 4;
    const int arow = blockIdx.x * 64 + wv * 16 + m16;

    f32x4v acc[8];
#pragma unroll
    for (int n = 0; n < 8; ++n) acc[n] = {0.f, 0.f, 0.f, 0.f};

#pragma unroll
    for (int k0 = 0; k0 < 128; k0 += 32) {
        short8v ah, al;
        if (arow < M) {
            const float4 a0 = *reinterpret_cast<const float4*>(
                X + (size_t)arow * 128 + k0 + g * 8);
            const float4 a1 = *reinterpret_cast<const float4*>(
                X + (size_t)arow * 128 + k0 + g * 8 + 4);
            const float f[8] = {a0.x, a0.y, a0.z, a0.w, a1.x, a1.y, a1.z, a1.w};
#pragma unroll
            for (int e = 0; e < 8; ++e) {
                const unsigned short h = f2bf_rne(f[e]);
                ah[e] = (short)h;
                al[e] = (short)f2bf_rne(f[e] - bf2f(h));
            }
        } else {
#pragma unroll
            for (int e = 0; e < 8; ++e) { ah[e] = 0; al[e] = 0; }
        }

#pragma unroll
        for (int n = 0; n < 8; ++n) {
            const short8v bh = *reinterpret_cast<const short8v*>(
                w1th + (n * 16 + m16) * 128 + k0 + g * 8);
            const short8v bl = *reinterpret_cast<const short8v*>(
                w1tl + (n * 16 + m16) * 128 + k0 + g * 8);
            acc[n] = __builtin_amdgcn_mfma_f32_16x16x32_bf16(ah, bh, acc[n], 0, 0, 0);
            acc[n] = __builtin_amdgcn_mfma_f32_16x16x32_bf16(al, bh, acc[n], 0, 0, 0);
            acc[n] = __builtin_amdgcn_mfma_f32_16x16x32_bf16(ah, bl, acc[n], 0, 0, 0);
        }
    }

#pragma unroll
    for (int r = 0; r < 4; ++r) {
        const int orow = blockIdx.x * 64 + wv * 16 + g * 4 + r;
        if (orow < M) {
#pragma unroll
            for (int n = 0; n < 8; ++n)
                Y[(size_t)orow * 128 + n * 16 + m16] = f2bf_rne(acc[n][r]);
        }
    }
}

// Sharded count: block b handles edge tile [b*CTILE, b*CTILE+CTILE), shard
// c = b&7 (round-robin block->XCD => atomics XCD-L2-local).
// rank[e] = rank of e within its (c, dst) group.
__global__ __launch_bounds__(256) void k_count8(const int* __restrict__ ei,
                                                int* __restrict__ indeg8,
                                                int* __restrict__ rank,
                                                int E, int N) {
    const bool is64 = probe_is64(ei);
    const int c = blockIdx.x & (NSH - 1);
    int* __restrict__ deg = indeg8 + (size_t)c * N;
    const int e0 = blockIdx.x * CTILE + threadIdx.x * 4;
    if (e0 >= E) return;
    const int n = min(4, E - e0);
    int d[4];
    load_idx4(ei, is64, (long long)E, e0, n, d);
    if (n == 4) {
        int4 r;
        r.x = atomicAdd(&deg[d[0]], 1);
        r.y = atomicAdd(&deg[d[1]], 1);
        r.z = atomicAdd(&deg[d[2]], 1);
        r.w = atomicAdd(&deg[d[3]], 1);
        *reinterpret_cast<int4*>(rank + e0) = r;
    } else {
        for (int j = 0; j < n; ++j)
            rank[e0 + j] = atomicAdd(&deg[d[j]], 1);
    }
}

// Per node: 8 shard counts -> in-place per-shard prefixes, total deg, dinv;
// exclusive scan of deg over nodes -> row_ptr (block-local) + partials.
__global__ __launch_bounds__(256) void k_scan1(int* __restrict__ indeg8,
                                               int* __restrict__ row_ptr,
                                               float* __restrict__ dinv,
                                               int* __restrict__ partials, int N) {
    const int t    = threadIdx.x;
    const int base = blockIdx.x * SCAN_CHUNK + t * 16;
    int v[16];
#pragma unroll
    for (int j = 0; j < 16; ++j) {
        const int d = base + j;
        int deg = 0;
        if (d < N) {
            int pre = 0;
#pragma unroll
            for (int c = 0; c < NSH; ++c) {
                const size_t idx = (size_t)c * N + d;
                const int cnt = indeg8[idx];
                indeg8[idx] = pre;     // per-shard prefix, in place
                pre += cnt;
            }
            deg = pre;
            dinv[d] = rsqrtf((float)(deg + 1));
        }
        v[j] = deg;
    }

    int sum = 0;
#pragma unroll
    for (int j = 0; j < 16; ++j) { const int tv = v[j]; v[j] = sum; sum += tv; }

    int incl = sum;
#pragma unroll
    for (int off = 1; off < 64; off <<= 1) {
        int tt = __shfl_up(incl, off, 64);
        if ((t & 63) >= off) incl += tt;
    }
    __shared__ int wsum[4];
    if ((t & 63) == 63) wsum[t >> 6] = incl;
    __syncthreads();
    int woff = 0;
#pragma unroll
    for (int w = 0; w < 4; ++w) woff += (w < (t >> 6)) ? wsum[w] : 0;
    const int texcl = woff + incl - sum;

#pragma unroll
    for (int j = 0; j < 16; ++j)
        if (base + j < N) row_ptr[base + j] = texcl + v[j];
    if (t == 255) partials[blockIdx.x] = woff + incl;
}

// Apply block offsets to row_ptr; emit base8[d*8+c] = row_ptr[d] + prefix[c][d];
// last block writes row_ptr[N].
__global__ __launch_bounds__(256) void k_scan3(const int* __restrict__ partials,
                                               int* __restrict__ row_ptr,
                                               const int* __restrict__ indeg8,
                                               int* __restrict__ base8,
                                               int N, int nblk) {
    int off = 0;
    for (int w = 0; w < (int)blockIdx.x; ++w) off += partials[w];

    const int base = blockIdx.x * SCAN_CHUNK + threadIdx.x * 16;
#pragma unroll
    for (int j = 0; j < 16; ++j) {
        const int d = base + j;
        if (d < N) {
            const int rp = row_ptr[d] + off;
            row_ptr[d] = rp;
            int4 b0, b1;
            b0.x = rp + indeg8[(size_t)0 * N + d];
            b0.y = rp + indeg8[(size_t)1 * N + d];
            b0.z = rp + indeg8[(size_t)2 * N + d];
            b0.w = rp + indeg8[(size_t)3 * N + d];
            b1.x = rp + indeg8[(size_t)4 * N + d];
            b1.y = rp + indeg8[(size_t)5 * N + d];
            b1.z = rp + indeg8[(size_t)6 * N + d];
            b1.w = rp + indeg8[(size_t)7 * N + d];
            reinterpret_cast<int4*>(base8 + (size_t)d * 8)[0] = b0;
            reinterpret_cast<int4*>(base8 + (size_t)d * 8)[1] = b1;
        }
    }
    if ((int)blockIdx.x == nblk - 1 && threadIdx.x == 255)
        row_ptr[N] = off + partials[nblk - 1];
}

// STANDALONE atomic-free fill: csr[base8[8d+c] + rank[e]] = {src, dinv_bits}.
// c recomputed from edge position: c = (e>>10)&7 (CTILE=1024).
__global__ __launch_bounds__(256) void k_fill(
    const int* __restrict__ ei, const int* __restrict__ rank,
    const int* __restrict__ base8, const float* __restrict__ dinv,
    int2* __restrict__ csr, int E) {
    const bool is64 = probe_is64(ei);
    const int idx    = blockIdx.x * blockDim.x + threadIdx.x;
    const int stride = gridDim.x * blockDim.x;
    for (int e0 = idx * 4; e0 < E; e0 += stride * 4) {
        const int n = min(4, E - e0);
        const int c = (e0 >> 10) & (NSH - 1);
        int s[4], d[4], rk[4];
        load_idx4(ei, is64, 0,            e0, n, s);
        load_idx4(ei, is64, (long long)E, e0, n, d);
        if (n == 4) {
            const int4 r = *reinterpret_cast<const int4*>(rank + e0);
            rk[0] = r.x; rk[1] = r.y; rk[2] = r.z; rk[3] = r.w;
        } else {
            for (int j = 0; j < n; ++j) rk[j] = rank[e0 + j];
        }
        int pos[4];
        float w[4];
        for (int j = 0; j < n; ++j) pos[j] = base8[(size_t)d[j] * 8 + c] + rk[j];
        for (int j = 0; j < n; ++j) w[j] = dinv[s[j]];
        for (int j = 0; j < n; ++j)
            csr[pos[j]] = make_int2(s[j], __float_as_int(w[j]));
    }
}

// FUSED gather1 + bias + ReLU + MFMA GEMM2 -> h2b (bf16). 64 nodes/block.
__global__ __launch_bounds__(256) void k_gather_gemm2(
    const unsigned short* __restrict__ h1b, const int* __restrict__ row_ptr,
    const int2* __restrict__ csr, const float* __restrict__ dinv,
    const float* __restrict__ b1,
    const unsigned short* __restrict__ w2th, const unsigned short* __restrict__ w2tl,
    unsigned short* __restrict__ h2b, int N) {
    constexpr int XSS = 136;
    __shared__ __align__(16) unsigned short xs[64 * XSS];

    const int tid  = threadIdx.x;
    const int r    = tid >> 2;
    const int lane = tid & 3;
    const int node = blockIdx.x * 64 + r;
    const int c0   = lane * 32;

    float4 acc[8];
    if (node < N) {
#pragma unroll
        for (int q = 0; q < 8; ++q)
            acc[q] = reinterpret_cast<const float4*>(b1 + c0)[q];
        const float dn = dinv[node];
        {
            const float ws = dn * dn;
            const uint4* hp = reinterpret_cast<const uint4*>(h1b + (size_t)node * HID + c0);
#pragma unroll
            for (int q = 0; q < 4; ++q) fma8(acc[2 * q], acc[2 * q + 1], hp[q], ws);
        }
        const int e1 = row_ptr[node + 1];
        int e = row_ptr[node];
        for (; e + 1 < e1; e += 2) {
            const int2 r0 = csr[e];
            const int2 r1 = csr[e + 1];
            const float w0 = __int_as_float(r0.y) * dn;
            const float w1 = __int_as_float(r1.y) * dn;
            const uint4* s0 = reinterpret_cast<const uint4*>(h1b + (size_t)r0.x * HID + c0);
            const uint4* s1 = reinterpret_cast<const uint4*>(h1b + (size_t)r1.x * HID + c0);
#pragma unroll
            for (int q = 0; q < 4; ++q) fma8(acc[2 * q], acc[2 * q + 1], s0[q], w0);
#pragma unroll
            for (int q = 0; q < 4; ++q) fma8(acc[2 * q], acc[2 * q + 1], s1[q], w1);
        }
        if (e < e1) {
            const int2 r0 = csr[e];
            const float w0 = __int_as_float(r0.y) * dn;
            const uint4* s0 = reinterpret_cast<const uint4*>(h1b + (size_t)r0.x * HID + c0);
#pragma unroll
            for (int q = 0; q < 4; ++q) fma8(acc[2 * q], acc[2 * q + 1], s0[q], w0);
        }
    } else {
#pragma unroll
        for (int q = 0; q < 8; ++q) acc[q] = make_float4(0.f, 0.f, 0.f, 0.f);
    }

#pragma unroll
    for (int q = 0; q < 8; ++q) {
        float4 a = acc[q];
        ushort4 o;
        o.x = f2bf_rne(fmaxf(a.x, 0.f));
        o.y = f2bf_rne(fmaxf(a.y, 0.f));
        o.z = f2bf_rne(fmaxf(a.z, 0.f));
        o.w = f2bf_rne(fmaxf(a.w, 0.f));
        *reinterpret_cast<ushort4*>(&xs[r * XSS + c0 + 4 * q]) = o;
    }
    __syncthreads();

    const int wv  = tid >> 6;
    const int ln  = tid & 63;
    const int m16 = ln & 15;
    const int g   = ln >> 4;

    f32x4v acc2[4];
#pragma unroll
    for (int n = 0; n < 4; ++n) acc2[n] = {0.f, 0.f, 0.f, 0.f};

#pragma unroll
    for (int k0 = 0; k0 < 128; k0 += 32) {
        const short8v a = *reinterpret_cast<const short8v*>(
            &xs[(wv * 16 + m16) * XSS + k0 + g * 8]);
#pragma unroll
        for (int n = 0; n < 4; ++n) {
            const short8v bh = *reinterpret_cast<const short8v*>(
                w2th + (n * 16 + m16) * 128 + k0 + g * 8);
            const short8v bl = *reinterpret_cast<const short8v*>(
                w2tl + (n * 16 + m16) * 128 + k0 + g * 8);
            acc2[n] = __builtin_amdgcn_mfma_f32_16x16x32_bf16(a, bh, acc2[n], 0, 0, 0);
            acc2[n] = __builtin_amdgcn_mfma_f32_16x16x32_bf16(a, bl, acc2[n], 0, 0, 0);
        }
    }

#pragma unroll
    for (int rr = 0; rr < 4; ++rr) {
        const int orow = blockIdx.x * 64 + wv * 16 + g * 4 + rr;
        if (orow < N) {
#pragma unroll
            for (int n = 0; n < 4; ++n)
                h2b[(size_t)orow * OUT_CH + n * 16 + m16] = f2bf_rne(acc2[n][rr]);
        }
    }
}

// out[n](f32) = b2 + h[n]*dinv[n]^2 + sum_e h[rec.src]*rec.w*dinv[n]
__global__ __launch_bounds__(256) void k_gather64(
    const unsigned short* __restrict__ h, const int* __restrict__ row_ptr,
    const int2* __restrict__ csr, const float* __restrict__ dinv,
    const float* __restrict__ b, float* __restrict__ out, int N) {
    constexpr int LPN = OUT_CH / 4;
    const int tid  = blockIdx.x * blockDim.x + threadIdx.x;
    const int node = tid / LPN;
    const int lane = tid % LPN;
    if (node >= N) return;

    const float dn = dinv[node];
    float4 acc = reinterpret_cast<const float4*>(b)[lane];
    {
        const float w = dn * dn;
        const ushort4 v = *reinterpret_cast<const ushort4*>(h + (size_t)node * OUT_CH + lane * 4);
        acc.x = fmaf(bf2f(v.x), w, acc.x); acc.y = fmaf(bf2f(v.y), w, acc.y);
        acc.z = fmaf(bf2f(v.z), w, acc.z); acc.w = fmaf(bf2f(v.w), w, acc.w);
    }

    const int e1 = row_ptr[node + 1];
    int e = row_ptr[node];
    for (; e + 1 < e1; e += 2) {
        const int2 r0 = csr[e];
        const int2 r1 = csr[e + 1];
        const float w0 = __int_as_float(r0.y) * dn;
        const float w1 = __int_as_float(r1.y) * dn;
        const ushort4 v0 = *reinterpret_cast<const ushort4*>(h + (size_t)r0.x * OUT_CH + lane * 4);
        const ushort4 v1 = *reinterpret_cast<const ushort4*>(h + (size_t)r1.x * OUT_CH + lane * 4);
        acc.x = fmaf(bf2f(v0.x), w0, acc.x); acc.y = fmaf(bf2f(v0.y), w0, acc.y);
        acc.z = fmaf(bf2f(v0.z), w0, acc.z); acc.w = fmaf(bf2f(v0.w), w0, acc.w);
        acc.x = fmaf(bf2f(v1.x), w1, acc.x); acc.y = fmaf(bf2f(v1.y), w1, acc.y);
        acc.z = fmaf(bf2f(v1.z), w1, acc.z); acc.w = fmaf(bf2f(v1.w), w1, acc.w);
    }
    if (e < e1) {
        const int2 r0 = csr[e];
        const float w0 = __int_as_float(r0.y) * dn;
        const ushort4 v0 = *reinterpret_cast<const ushort4*>(h + (size_t)r0.x * OUT_CH + lane * 4);
        acc.x = fmaf(bf2f(v0.x), w0, acc.x); acc.y = fmaf(bf2f(v0.y), w0, acc.y);
        acc.z = fmaf(bf2f(v0.z), w0, acc.z); acc.w = fmaf(bf2f(v0.w), w0, acc.w);
    }

    reinterpret_cast<float4*>(out + (size_t)node * OUT_CH)[lane] = acc;
}

extern "C" void kernel_launch(void* const* d_in, const int* in_sizes, int n_in,
                              void* d_out, int out_size, void* d_ws, size_t ws_size,
                              hipStream_t stream) {
    const float* x  = (const float*)d_in[0];
    const int*   ei = (const int*)d_in[1];
    const float* W1 = (const float*)d_in[2];
    const float* b1 = (const float*)d_in[3];
    const float* W2 = (const float*)d_in[4];
    const float* b2 = (const float*)d_in[5];
    float* out = (float*)d_out;

    const int N  = in_sizes[0] / IN_CH;   // 50000
    const int E  = in_sizes[1] / 2;       // 600000
    const int M8 = NSH * N;
    const int NBLK = (N + SCAN_CHUNK - 1) / SCAN_CHUNK;   // 13
    const int CNTBLK = (E + CTILE - 1) / CTILE;           // 586

    char* wsb = (char*)d_ws;
    size_t off = 0;
    auto alloc = [&](size_t bytes) -> void* {
        void* p = wsb + off;
        off += (bytes + 255) & ~(size_t)255;
        return p;
    };
    int*   indeg8   = (int*)alloc((size_t)M8 * sizeof(int));
    int*   base8    = (int*)alloc((size_t)M8 * sizeof(int));
    int*   rank     = (int*)alloc((size_t)E * sizeof(int));
    int*   partials = (int*)alloc(64 * sizeof(int));
    float* dinv     = (float*)alloc((size_t)N * sizeof(float));
    int*   row_ptr  = (int*)alloc(((size_t)N + 1) * sizeof(int));
    int2*  csr      = (int2*)alloc((size_t)E * sizeof(int2));
    unsigned short* w1th = (unsigned short*)alloc(128 * 128 * sizeof(unsigned short));
    unsigned short* w1tl = (unsigned short*)alloc(128 * 128 * sizeof(unsigned short));
    unsigned short* w2th = (unsigned short*)alloc(64 * 128 * sizeof(unsigned short));
    unsigned short* w2tl = (unsigned short*)alloc(64 * 128 * sizeof(unsigned short));
    unsigned short* h1b  = (unsigned short*)alloc((size_t)N * HID * sizeof(unsigned short));
    unsigned short* h2b  = (unsigned short*)alloc((size_t)N * OUT_CH * sizeof(unsigned short));

    auto gs = [](long long n) { return (int)((n + 255) / 256); };

    k_init<<<88, 256, 0, stream>>>(indeg8, M8, W1, W2, w1th, w1tl, w2th, w2tl);

    // standalone attribution targets
    k_gemm1<<<(N + 63) / 64, 256, 0, stream>>>(x, w1th, w1tl, h1b, N);
    k_count8<<<CNTBLK, 256, 0, stream>>>(ei, indeg8, rank, E, N);

    k_scan1<<<NBLK, 256, 0, stream>>>(indeg8, row_ptr, dinv, partials, N);
    k_scan3<<<NBLK, 256, 0, stream>>>(partials, row_ptr, indeg8, base8, N, NBLK);

    k_fill<<<1024, 256, 0, stream>>>(ei, rank, base8, dinv, csr, E);

    k_gather_gemm2<<<(N + 63) / 64, 256, 0, stream>>>(
        h1b, row_ptr, csr, dinv, b1, w2th, w2tl, h2b, N);

    k_gather64<<<gs((long long)N * (OUT_CH / 4)), 256, 0, stream>>>(
        h2b, row_ptr, csr, dinv, b2, out, N);
}